// Round 9
// baseline (632.544 us; speedup 1.0000x reference)
//
#include <hip/hip_runtime.h>

// UnMaxPoolWithArgmax, two-pass counting-sort at window granularity:
//   passA: per 8192-elem sub-batch (one image batch b each), LDS-sort records
//          by 1024 in-batch window buckets ((tg>>14)&1023); flush contiguous
//          u64 records (rel14<<32 | valbits) + u16 offset directory (amp ~1).
//   tposeD: transpose directory to window-major (2x16 MB, trivial).
//   passC: one block per 2^14-slot window (8192 blocks, 64KB acc -> 2
//          blocks/CU); single sweep, 8-deep UNCONDITIONAL load batches per
//          16-lane group (atomics stay predicated), LDS atomicAdd once per
//          record, nontemporal 64 KB store. Covers whole output.
// target tg = (b<<24) | (mask & ~63) | c0 (27 bits); window = tg>>14 (8192).

typedef unsigned int u32;
typedef unsigned short u16;
typedef unsigned long long u64;

// clang ext-vector types (valid for __builtin_nontemporal_load/store)
typedef int   iv4 __attribute__((ext_vector_type(4)));
typedef float fv4 __attribute__((ext_vector_type(4)));

constexpr long long N_IN = 1LL << 26;      // 67,108,864 elements
constexpr int SBS   = 8192;                // elements per sub-batch
constexpr int NSB   = (int)(N_IN / SBS);   // 8192 sub-batches
constexpr int NBKT  = 1024;                // in-batch window buckets
constexpr int NWIN  = 8192;                // global windows (8 batches * 1024)
constexpr int RSH   = 14;                  // window = 2^14 slots (64 KiB)
constexpr int RSLOTS = 1 << RSH;
constexpr int SB_PER_B = 1024;             // sub-batches per image batch

// ---------------- workspace ----------------
constexpr size_t OFF_RECA = 0;                                   // u64[2^26] = 512 MiB
constexpr size_t OFF_DIR  = (size_t)N_IN * 8;                    // u16[NSB*NBKT] = 16 MiB
constexpr size_t OFF_DIRT = OFF_DIR + (size_t)NSB * NBKT * 2;    // u16[NWIN*SB_PER_B] = 16 MiB
constexpr size_t WS_FUSED = OFF_DIRT + (size_t)NWIN * SB_PER_B * 2;  // ~544 MiB
// note: passC may read up to 15 u64 past recA's end (empty last chunk,
// unconditional load); that lands in the dir region -> in-bounds of ws.

// ============================ passA ============================
__global__ __launch_bounds__(512) void passA(const float* __restrict__ in,
                                             const int* __restrict__ mask,
                                             u64* __restrict__ recA,
                                             u16* __restrict__ dir)
{
    __shared__ u32 cur[NBKT];      // hist -> starts -> cursors (4 KiB)
    __shared__ u32 wsum[8];
    __shared__ u64 sRec[SBS];      // 64 KiB
    const int tid = threadIdx.x;
    const int sb  = blockIdx.x;
    const int e0  = sb * SBS + tid * 16;

    const iv4* m4 = (const iv4*)mask + (e0 >> 2);
    const fv4* v4 = (const fv4*)in + (e0 >> 2);
    iv4 m0 = __builtin_nontemporal_load(m4 + 0);
    iv4 m1 = __builtin_nontemporal_load(m4 + 1);
    iv4 m2 = __builtin_nontemporal_load(m4 + 2);
    iv4 m3 = __builtin_nontemporal_load(m4 + 3);
    fv4 va = __builtin_nontemporal_load(v4 + 0);
    fv4 vb = __builtin_nontemporal_load(v4 + 1);
    fv4 vc = __builtin_nontemporal_load(v4 + 2);
    fv4 vd = __builtin_nontemporal_load(v4 + 3);
    const u32 bbits = ((u32)(e0 >> 23)) << 24;   // batch bits (HWC = 2^23)
    const u32 c0 = (u32)(e0 & 63);

    u32 tg[16]; float vv[16];
    tg[ 0] = bbits + (((u32)m0.x) & ~63u) + c0 +  0; vv[ 0] = va.x;
    tg[ 1] = bbits + (((u32)m0.y) & ~63u) + c0 +  1; vv[ 1] = va.y;
    tg[ 2] = bbits + (((u32)m0.z) & ~63u) + c0 +  2; vv[ 2] = va.z;
    tg[ 3] = bbits + (((u32)m0.w) & ~63u) + c0 +  3; vv[ 3] = va.w;
    tg[ 4] = bbits + (((u32)m1.x) & ~63u) + c0 +  4; vv[ 4] = vb.x;
    tg[ 5] = bbits + (((u32)m1.y) & ~63u) + c0 +  5; vv[ 5] = vb.y;
    tg[ 6] = bbits + (((u32)m1.z) & ~63u) + c0 +  6; vv[ 6] = vb.z;
    tg[ 7] = bbits + (((u32)m1.w) & ~63u) + c0 +  7; vv[ 7] = vb.w;
    tg[ 8] = bbits + (((u32)m2.x) & ~63u) + c0 +  8; vv[ 8] = vc.x;
    tg[ 9] = bbits + (((u32)m2.y) & ~63u) + c0 +  9; vv[ 9] = vc.y;
    tg[10] = bbits + (((u32)m2.z) & ~63u) + c0 + 10; vv[10] = vc.z;
    tg[11] = bbits + (((u32)m2.w) & ~63u) + c0 + 11; vv[11] = vc.w;
    tg[12] = bbits + (((u32)m3.x) & ~63u) + c0 + 12; vv[12] = vd.x;
    tg[13] = bbits + (((u32)m3.y) & ~63u) + c0 + 13; vv[13] = vd.y;
    tg[14] = bbits + (((u32)m3.z) & ~63u) + c0 + 14; vv[14] = vd.z;
    tg[15] = bbits + (((u32)m3.w) & ~63u) + c0 + 15; vv[15] = vd.w;

    cur[2 * tid] = 0;
    cur[2 * tid + 1] = 0;
    __syncthreads();
#pragma unroll
    for (int j = 0; j < 16; ++j) atomicAdd(&cur[(tg[j] >> RSH) & (NBKT - 1)], 1u);
    __syncthreads();

    // exclusive scan of 1024 counters (2 consecutive per thread)
    {
        const int lane = tid & 63;
        const int wid  = tid >> 6;
        u32 a = cur[2 * tid];
        u32 b = cur[2 * tid + 1];
        u32 sum = a + b;
        u32 s = sum;
#pragma unroll
        for (int d = 1; d < 64; d <<= 1) {
            u32 n = __shfl_up(s, (unsigned)d, 64);
            if (lane >= d) s += n;
        }
        if (lane == 63) wsum[wid] = s;
        u32 exw = s - sum;
        __syncthreads();
        if (tid == 0) {
            u32 run = 0;
#pragma unroll
            for (int w = 0; w < 8; ++w) { u32 t2 = wsum[w]; wsum[w] = run; run += t2; }
        }
        __syncthreads();
        u32 start = wsum[wid] + exw;
        dir[(size_t)sb * NBKT + 2 * tid]     = (u16)start;
        dir[(size_t)sb * NBKT + 2 * tid + 1] = (u16)(start + a);
        cur[2 * tid]     = start;          // cursors
        cur[2 * tid + 1] = start + a;
    }
    __syncthreads();

#pragma unroll
    for (int j = 0; j < 16; ++j) {
        u32 p = atomicAdd(&cur[(tg[j] >> RSH) & (NBKT - 1)], 1u);
        sRec[p] = ((u64)(tg[j] & (RSLOTS - 1)) << 32) | (u64)__float_as_uint(vv[j]);
    }
    __syncthreads();
#pragma unroll
    for (int k = 0; k < 16; ++k) {
        int i = tid + k * 512;
        recA[(size_t)sb * SBS + i] = sRec[i];    // contiguous u64 flush
    }
}

// ============================ directory transpose ============================
// dir[bb*1024+sb][1024 lb] -> dirT[bb*1024+lb][1024 sb]; 64x64 u16 tiles.
__global__ __launch_bounds__(256) void tposeD(const u16* __restrict__ dir,
                                              u16* __restrict__ dirT)
{
    __shared__ u16 t[64][65];
    const int tx = threadIdx.x;        // 0..63
    const int ty = threadIdx.y;        // 0..3
    const int bb = blockIdx.z;
    const int sb0 = blockIdx.x * 64;   // 16 tiles
    const int lb0 = blockIdx.y * 64;   // 16 tiles
#pragma unroll
    for (int k = 0; k < 16; ++k) {
        int row = k * 4 + ty;          // sb within tile
        t[row][tx] = dir[((size_t)(bb * SB_PER_B + sb0 + row)) * NBKT + lb0 + tx];
    }
    __syncthreads();
#pragma unroll
    for (int k = 0; k < 16; ++k) {
        int row = k * 4 + ty;          // lb within tile
        dirT[((size_t)(bb * NBKT + lb0 + row)) * SB_PER_B + sb0 + tx] = t[tx][row];
    }
}

// ============================ passC ============================
__global__ __launch_bounds__(1024, 8) void passC(const u64* __restrict__ recA,
                                                 const u16* __restrict__ dirT,
                                                 float* __restrict__ out)
{
    __shared__ float acc[RSLOTS];      // 64 KiB
    __shared__ u32 cSrc[SB_PER_B];     // 4 KiB
    __shared__ u16 cLen[SB_PER_B];     // 2 KiB
    const int tid = threadIdx.x;
    const int bid = blockIdx.x;
    const int w   = ((bid & 7) << 10) | (bid >> 3);  // XCD-chunked bijective swizzle
    const int bb  = w >> 10;
    const int lb  = w & (NBKT - 1);

    {   // chunk table: two contiguous directory rows
        u32 st = dirT[(size_t)w * SB_PER_B + tid];
        u32 en = (lb == NBKT - 1) ? (u32)SBS : (u32)dirT[(size_t)(w + 1) * SB_PER_B + tid];
        cSrc[tid] = (u32)(bb * SB_PER_B + tid) * (u32)SBS + st;
        cLen[tid] = (u16)(en - st);
    }
    {   // vectorized zero of the accumulator
        fv4 z = {0.f, 0.f, 0.f, 0.f};
        fv4* av = (fv4*)acc;
#pragma unroll
        for (int i = tid; i < RSLOTS / 4; i += 1024) av[i] = z;
    }
    __syncthreads();

    // 64 groups of 16 lanes; group g owns chunks g + 64*j, j=0..15, processed
    // in 2 rounds of 8. Loads are UNCONDITIONAL (any chunk base is a valid
    // address; worst case reads bleed <=15 u64 into the dir region of ws) and
    // fully unrolled with static register arrays -> 8 independent loads in
    // flight per wave. Atomics are predicated by true length. Tail loops
    // (len>16, P~0.2% per chunk) handled after.
    const int g  = tid >> 4;
    const int gl = tid & 15;
#pragma unroll
    for (int r = 0; r < 2; ++r) {
        u32 src[8]; int len[8]; u64 rec[8];
#pragma unroll
        for (int j = 0; j < 8; ++j) {
            int s = g + (r * 8 + j) * 64;
            src[j] = cSrc[s];
            len[j] = (int)cLen[s];
        }
#pragma unroll
        for (int j = 0; j < 8; ++j) rec[j] = recA[src[j] + gl];   // 8-deep MLP
#pragma unroll
        for (int j = 0; j < 8; ++j) {
            if (gl < len[j])
                atomicAdd(&acc[(u32)(rec[j] >> 32)], __uint_as_float((u32)rec[j]));
        }
#pragma unroll
        for (int j = 0; j < 8; ++j) {
            for (int off = gl + 16; off < len[j]; off += 16) {    // rare tail
                u64 rc = recA[src[j] + off];
                atomicAdd(&acc[(u32)(rc >> 32)], __uint_as_float((u32)rc));
            }
        }
    }
    __syncthreads();

    // nontemporal store: output is written once, never re-read this launch;
    // keeps record lines resident in L2/L3 for other blocks' gathers.
    fv4* o4 = (fv4*)out + ((size_t)w << (RSH - 2));
    const fv4* a4 = (const fv4*)acc;
#pragma unroll
    for (int i = tid; i < RSLOTS / 4; i += 1024)
        __builtin_nontemporal_store(a4[i], o4 + i);
}

// ===================== fallback: direct atomic scatter =====================
__global__ __launch_bounds__(256) void unmaxpool_scatter(
    const float* __restrict__ in, const int* __restrict__ mask,
    float* __restrict__ out)
{
    const long long n4 = N_IN / 4;
    long long gidx = (long long)blockIdx.x * blockDim.x + threadIdx.x;
    const long long stride = (long long)gridDim.x * blockDim.x;
    for (; gidx < n4; gidx += stride) {
        float4 v = reinterpret_cast<const float4*>(in)[gidx];
        int4 m = reinterpret_cast<const int4*>(mask)[gidx];
        long long i0 = gidx * 4;
        u32 ob = ((u32)(i0 >> 23)) << 24;
        u32 c0 = (u32)(i0 & 63);
        atomicAdd(&out[ob + (u32)(m.x & ~63) + c0 + 0], v.x);
        atomicAdd(&out[ob + (u32)(m.y & ~63) + c0 + 1], v.y);
        atomicAdd(&out[ob + (u32)(m.z & ~63) + c0 + 2], v.z);
        atomicAdd(&out[ob + (u32)(m.w & ~63) + c0 + 3], v.w);
    }
}

extern "C" void kernel_launch(void* const* d_in, const int* in_sizes, int n_in,
                              void* d_out, int out_size, void* d_ws, size_t ws_size,
                              hipStream_t stream) {
    const float* in = (const float*)d_in[0];
    const int* mask = (const int*)d_in[1];
    float* out = (float*)d_out;
    char* ws = (char*)d_ws;

    if (d_ws != nullptr && ws_size >= WS_FUSED) {
        u64* recA = (u64*)(ws + OFF_RECA);
        u16* dir  = (u16*)(ws + OFF_DIR);
        u16* dirT = (u16*)(ws + OFF_DIRT);
        passA<<<NSB, 512, 0, stream>>>(in, mask, recA, dir);
        tposeD<<<dim3(16, 16, 8), dim3(64, 4), 0, stream>>>(dir, dirT);
        passC<<<NWIN, 1024, 0, stream>>>(recA, dirT, out);
    } else {
        (void)hipMemsetAsync(out, 0, (size_t)out_size * sizeof(float), stream);
        unmaxpool_scatter<<<2048, 256, 0, stream>>>(in, mask, out);
    }
}